// Round 3
// baseline (277.133 us; speedup 1.0000x reference)
//
#include <hip/hip_runtime.h>
#include <hip/hip_bf16.h>
#include <stdint.h>

#define B_ROWS 16384   // batch rows (M)
#define C_ROWS 2048    // class rows (N)
#define D_FULL 512     // input feature dim
#define KP     512     // padded K (511 real + 1 zero col)

#define BM 128
#define BN 128

typedef __attribute__((ext_vector_type(8))) short bf16x8;
typedef __attribute__((ext_vector_type(4))) float f32x4;

// ---------------------------------------------------------------------------
// Prep: per row, cast cols [1..511] -> bf16 (padded to 512 with trailing 0),
// and compute norm = sqrt(1 + sum(rest^2)) in fp32.
// One 256-thread block per row; thread t handles k = 2t, 2t+1 (ushort2 store).
// ---------------------------------------------------------------------------
__global__ __launch_bounds__(256) void prep_kernel(
    const float* __restrict__ x, const float* __restrict__ pts,
    unsigned short* __restrict__ Abf, unsigned short* __restrict__ Bbf,
    float* __restrict__ xn, float* __restrict__ pn)
{
    int row = blockIdx.x;
    const float* src;
    unsigned short* dst;
    float* nrm;
    if (row < B_ROWS) {
        src = x + (size_t)row * D_FULL;
        dst = Abf + (size_t)row * KP;
        nrm = xn + row;
    } else {
        int r = row - B_ROWS;
        src = pts + (size_t)r * D_FULL;
        dst = Bbf + (size_t)r * KP;
        nrm = pn + r;
    }
    int t = threadIdx.x;
    float v0 = src[2 * t + 1];                        // k = 2t
    float v1 = (t < 255) ? src[2 * t + 2] : 0.0f;     // k = 2t+1 (k==511 -> pad 0)
    __hip_bfloat16 b0 = __float2bfloat16(v0);
    __hip_bfloat16 b1 = __float2bfloat16(v1);
    union { unsigned short u[2]; unsigned int w; } pack;
    pack.u[0] = *(unsigned short*)&b0;
    pack.u[1] = *(unsigned short*)&b1;
    *(unsigned int*)&dst[2 * t] = pack.w;             // 4B-aligned vector store
    float ss = v0 * v0 + v1 * v1;
    #pragma unroll
    for (int off = 32; off > 0; off >>= 1) ss += __shfl_down(ss, off);
    __shared__ float red[4];
    if ((t & 63) == 0) red[t >> 6] = ss;
    __syncthreads();
    if (t == 0) nrm[0] = sqrtf(1.0f + red[0] + red[1] + red[2] + red[3]);
}

// ---------------------------------------------------------------------------
// GEMM, no-LDS structure: C[m][n] = sum_k A[m][k]*B[n][k], both K-major.
// 128x128 block tile, 4 waves in 2x2, each wave 64x64 via 4x4 of 16x16x32.
// A/B operand layout for mfma_f32_16x16x32_bf16 is [row=lane&15][k=quad*8+j]
// == one global_load_dwordx4 per fragment from K-major storage. Fragments go
// DIRECT global->register (B is 2MB L2-resident; consecutive blocks share the
// A-tile via N-fastest grid). No LDS, no __syncthreads, no vmcnt(0) drain —
// loads software-pipelined one K-step ahead, compiler emits fine vmcnt(N).
// Epilogue: out = -arccosh(max(x0[m]*p0[n] - acc, 1+eps))
// ---------------------------------------------------------------------------
__global__ __launch_bounds__(256) void gemm_kernel(
    const unsigned short* __restrict__ A,   // [B_ROWS][KP] bf16
    const unsigned short* __restrict__ Bm,  // [C_ROWS][KP] bf16
    const float* __restrict__ xn, const float* __restrict__ pn,
    float* __restrict__ out)
{
    const int tid  = threadIdx.x;
    const int wave = tid >> 6;
    const int lane = tid & 63;
    const int wm   = wave >> 1;        // 0..1
    const int wn   = wave & 1;         // 0..1
    const int lrow = lane & 15;
    const int quad = lane >> 4;        // 0..3

    const int bn0 = blockIdx.x * BN;   // N fastest: consecutive blocks share A-tile in L2
    const int bm0 = blockIdx.y * BM;

    const unsigned short* aBase[4];
    const unsigned short* bBase[4];
    #pragma unroll
    for (int i = 0; i < 4; ++i) {
        aBase[i] = A  + (size_t)(bm0 + wm * 64 + i * 16 + lrow) * KP + quad * 8;
        bBase[i] = Bm + (size_t)(bn0 + wn * 64 + i * 16 + lrow) * KP + quad * 8;
    }

    f32x4 acc[4][4] = {};

    bf16x8 a_cur[4], b_cur[4];
    #pragma unroll
    for (int i = 0; i < 4; ++i) {
        a_cur[i] = *(const bf16x8*)(aBase[i]);
        b_cur[i] = *(const bf16x8*)(bBase[i]);
    }

    #pragma unroll 2
    for (int k = 32; k < KP; k += 32) {
        bf16x8 a_nxt[4], b_nxt[4];
        #pragma unroll
        for (int i = 0; i < 4; ++i) {
            a_nxt[i] = *(const bf16x8*)(aBase[i] + k);
            b_nxt[i] = *(const bf16x8*)(bBase[i] + k);
        }
        #pragma unroll
        for (int mi = 0; mi < 4; ++mi)
            #pragma unroll
            for (int ni = 0; ni < 4; ++ni)
                acc[mi][ni] = __builtin_amdgcn_mfma_f32_16x16x32_bf16(
                    a_cur[mi], b_cur[ni], acc[mi][ni], 0, 0, 0);
        #pragma unroll
        for (int i = 0; i < 4; ++i) { a_cur[i] = a_nxt[i]; b_cur[i] = b_nxt[i]; }
    }
    #pragma unroll
    for (int mi = 0; mi < 4; ++mi)
        #pragma unroll
        for (int ni = 0; ni < 4; ++ni)
            acc[mi][ni] = __builtin_amdgcn_mfma_f32_16x16x32_bf16(
                a_cur[mi], b_cur[ni], acc[mi][ni], 0, 0, 0);

    // epilogue: C/D layout col = lane&15, row = quad*4 + reg
    float pv[4];
    #pragma unroll
    for (int ni = 0; ni < 4; ++ni)
        pv[ni] = pn[bn0 + wn * 64 + ni * 16 + lrow];

    #pragma unroll
    for (int mi = 0; mi < 4; ++mi) {
        #pragma unroll
        for (int r = 0; r < 4; ++r) {
            int row = bm0 + wm * 64 + mi * 16 + quad * 4 + r;
            float xv = xn[row];
            size_t base = (size_t)row * C_ROWS + bn0 + wn * 64 + lrow;
            #pragma unroll
            for (int ni = 0; ni < 4; ++ni) {
                float z = fmaf(xv, pv[ni], -acc[mi][ni][r]);
                z = fmaxf(z, 1.0f + 1e-7f);
                // arccosh(z) = log(z + sqrt(z^2-1)); z >= ~20 here, no cancellation
                out[base + ni * 16] = -__logf(z + __fsqrt_rn(z * z - 1.0f));
            }
        }
    }
}

extern "C" void kernel_launch(void* const* d_in, const int* in_sizes, int n_in,
                              void* d_out, int out_size, void* d_ws, size_t ws_size,
                              hipStream_t stream) {
    const float* x   = (const float*)d_in[0];
    const float* pts = (const float*)d_in[1];
    float* out = (float*)d_out;

    char* ws = (char*)d_ws;
    unsigned short* Abf = (unsigned short*)ws;                                 // 16 MB
    unsigned short* Bbf = (unsigned short*)(ws + (size_t)B_ROWS * KP * 2);     // 2 MB
    float* xn = (float*)(ws + (size_t)(B_ROWS + C_ROWS) * KP * 2);             // 64 KB
    float* pn = (float*)((char*)xn + (size_t)B_ROWS * 4);                      // 8 KB
    (void)in_sizes; (void)n_in; (void)out_size; (void)ws_size;

    prep_kernel<<<B_ROWS + C_ROWS, 256, 0, stream>>>(x, pts, Abf, Bbf, xn, pn);

    dim3 grid(C_ROWS / BN, B_ROWS / BM);   // x = N-blocks (16), y = M-blocks (128)
    gemm_kernel<<<grid, 256, 0, stream>>>(Abf, Bbf, xn, pn, out);
}

// Round 4
// 201.941 us; speedup vs baseline: 1.3724x; 1.3724x over previous
//
#include <hip/hip_runtime.h>
#include <hip/hip_bf16.h>
#include <stdint.h>

#define B_ROWS 16384   // batch rows (M)
#define C_ROWS 2048    // class rows (N)
#define D_FULL 512     // input feature dim
#define KP     512     // padded K (511 real + 1 zero col)

#define BM 128
#define BN 128
#define BK 32          // one 16x16x32 K-step per iter; 16 iters; dbuf LDS = 32 KB

typedef __attribute__((ext_vector_type(8))) short bf16x8;
typedef __attribute__((ext_vector_type(4))) float f32x4;

typedef __attribute__((address_space(1))) void glb_void;
typedef __attribute__((address_space(3))) void lds_void;

// async global->LDS, 16B per lane; LDS dest = wave-uniform base + lane*16
__device__ __forceinline__ void gld16(const void* g, void* l) {
    __builtin_amdgcn_global_load_lds((glb_void*)(uintptr_t)g,
                                     (lds_void*)(uintptr_t)l, 16, 0, 0);
}

// ---------------------------------------------------------------------------
// Prep: per row, cast cols [1..511] -> bf16 (padded to 512 with trailing 0),
// and compute norm = sqrt(1 + sum(rest^2)) in fp32.
// ---------------------------------------------------------------------------
__global__ __launch_bounds__(256) void prep_kernel(
    const float* __restrict__ x, const float* __restrict__ pts,
    unsigned short* __restrict__ Abf, unsigned short* __restrict__ Bbf,
    float* __restrict__ xn, float* __restrict__ pn)
{
    int row = blockIdx.x;
    const float* src;
    unsigned short* dst;
    float* nrm;
    if (row < B_ROWS) {
        src = x + (size_t)row * D_FULL;
        dst = Abf + (size_t)row * KP;
        nrm = xn + row;
    } else {
        int r = row - B_ROWS;
        src = pts + (size_t)r * D_FULL;
        dst = Bbf + (size_t)r * KP;
        nrm = pn + r;
    }
    int t = threadIdx.x;
    float v0 = src[2 * t + 1];
    float v1 = (t < 255) ? src[2 * t + 2] : 0.0f;    // k==511 -> pad 0
    __hip_bfloat16 b0 = __float2bfloat16(v0);
    __hip_bfloat16 b1 = __float2bfloat16(v1);
    union { unsigned short u[2]; unsigned int w; } pack;
    pack.u[0] = *(unsigned short*)&b0;
    pack.u[1] = *(unsigned short*)&b1;
    *(unsigned int*)&dst[2 * t] = pack.w;
    float ss = v0 * v0 + v1 * v1;
    #pragma unroll
    for (int off = 32; off > 0; off >>= 1) ss += __shfl_down(ss, off);
    __shared__ float red[4];
    if ((t & 63) == 0) red[t >> 6] = ss;
    __syncthreads();
    if (t == 0) nrm[0] = sqrtf(1.0f + red[0] + red[1] + red[2] + red[3]);
}

// ---------------------------------------------------------------------------
// GEMM: C[m][n] = sum_k A[m][k]*B[n][k], both K-major. 128x128 tile, 4 waves
// 2x2, wave 64x64 via 4x4 of 16x16x32. DOUBLE-BUFFERED LDS, ONE barrier/iter:
//   barrier; stage(buf^1, k+1) async; compute(buf, k)
// so the vmcnt(0) drain at the next barrier waits on loads issued a full
// compute-phase earlier (overlap the m97 2-barrier structure can't express).
// XOR swizzle for 64B rows: 16B-chunk pos p of row r holds global chunk
// p ^ (r&3) ^ ((r>>2)&3)  -> fragment ds_read_b128 is bank-conflict-free.
// Epilogue: out = -arccosh(max(x0[m]*p0[n] - acc, 1+eps))
// ---------------------------------------------------------------------------
__global__ __launch_bounds__(256) void gemm_kernel(
    const unsigned short* __restrict__ A,   // [B_ROWS][KP] bf16
    const unsigned short* __restrict__ Bm,  // [C_ROWS][KP] bf16
    const float* __restrict__ xn, const float* __restrict__ pn,
    float* __restrict__ out)
{
    __shared__ unsigned short As[2][BM * BK];   // 2 x 8 KB
    __shared__ unsigned short Bs[2][BN * BK];   // 2 x 8 KB

    const int tid  = threadIdx.x;
    const int wave = tid >> 6;
    const int lane = tid & 63;
    const int wm   = wave >> 1;        // 0..1
    const int wn   = wave & 1;         // 0..1
    const int lrow = lane & 15;
    const int quad = lane >> 4;        // 0..3

    const int bm0 = blockIdx.x * BM;
    const int bn0 = blockIdx.y * BN;

    // Staging: row within 16-row group = lane>>2, chunk pos = lane&3.
    // Global source chunk = pos ^ (row&3) ^ ((row>>2)&3); for row = lane>>2
    // (+16*i, multiples of 16 don't change the XOR bits): 
    const int srow  = lane >> 2;                                   // 0..15
    const int schk  = (lane & 3) ^ (srow & 3) ^ ((lane >> 4) & 3); // permuted chunk
    const int scol  = schk << 3;                                   // element col in [0,32)

    const unsigned short* gA0 = A  + (size_t)(bm0 + wave * 32 + srow) * KP + scol;
    const unsigned short* gA1 = gA0 + (size_t)16 * KP;
    const unsigned short* gB0 = Bm + (size_t)(bn0 + wave * 32 + srow) * KP + scol;
    const unsigned short* gB1 = gB0 + (size_t)16 * KP;

    unsigned short* ldsA0 = &As[0][(wave * 32 + 0) * BK];
    unsigned short* ldsA1 = &As[0][(wave * 32 + 16) * BK];
    unsigned short* ldsB0 = &Bs[0][(wave * 32 + 0) * BK];
    unsigned short* ldsB1 = &Bs[0][(wave * 32 + 16) * BK];
    const int bufStride = BM * BK;   // elements per buffer

    // fragment read swizzle (lane-constant): chunk pos = quad ^ (lrow&3) ^ (lrow>>2)
    const int sw8 = ((quad ^ (lrow & 3) ^ (lrow >> 2)) & 3) << 3;

    int aoff[4], boff[4];
    #pragma unroll
    for (int i = 0; i < 4; ++i) {
        aoff[i] = (wm * 64 + i * 16 + lrow) * BK + sw8;
        boff[i] = (wn * 64 + i * 16 + lrow) * BK + sw8;
    }

    f32x4 acc[4][4] = {};

    // prologue: stage k-block 0 into buf 0
    gld16(gA0, ldsA0); gld16(gA1, ldsA1);
    gld16(gB0, ldsB0); gld16(gB1, ldsB1);

    #pragma unroll 2
    for (int it = 0; it < KP / BK; ++it) {
        const int buf = it & 1;
        __syncthreads();   // drains prev compute's ds_reads + buf's staging (issued last iter)
        if (it + 1 < KP / BK) {
            const int k1 = (it + 1) * BK;
            const int d  = (buf ^ 1) * bufStride;
            gld16(gA0 + k1, ldsA0 + d); gld16(gA1 + k1, ldsA1 + d);
            gld16(gB0 + k1, ldsB0 + d); gld16(gB1 + k1, ldsB1 + d);
        }
        bf16x8 af[4], bfr[4];
        #pragma unroll
        for (int i = 0; i < 4; ++i) {
            af[i]  = *(const bf16x8*)&As[buf][aoff[i]];
            bfr[i] = *(const bf16x8*)&Bs[buf][boff[i]];
        }
        #pragma unroll
        for (int mi = 0; mi < 4; ++mi)
            #pragma unroll
            for (int ni = 0; ni < 4; ++ni)
                acc[mi][ni] = __builtin_amdgcn_mfma_f32_16x16x32_bf16(
                    af[mi], bfr[ni], acc[mi][ni], 0, 0, 0);
    }

    // epilogue: C/D layout col = lane&15, row = quad*4 + reg
    float pv[4];
    #pragma unroll
    for (int ni = 0; ni < 4; ++ni)
        pv[ni] = pn[bn0 + wn * 64 + ni * 16 + lrow];

    #pragma unroll
    for (int mi = 0; mi < 4; ++mi) {
        #pragma unroll
        for (int r = 0; r < 4; ++r) {
            int row = bm0 + wm * 64 + mi * 16 + quad * 4 + r;
            float xv = xn[row];
            size_t base = (size_t)row * C_ROWS + bn0 + wn * 64 + lrow;
            #pragma unroll
            for (int ni = 0; ni < 4; ++ni) {
                float z = fmaf(xv, pv[ni], -acc[mi][ni][r]);
                z = fmaxf(z, 1.0f + 1e-7f);
                out[base + ni * 16] = -__logf(z + __fsqrt_rn(z * z - 1.0f));
            }
        }
    }
}

extern "C" void kernel_launch(void* const* d_in, const int* in_sizes, int n_in,
                              void* d_out, int out_size, void* d_ws, size_t ws_size,
                              hipStream_t stream) {
    const float* x   = (const float*)d_in[0];
    const float* pts = (const float*)d_in[1];
    float* out = (float*)d_out;

    char* ws = (char*)d_ws;
    unsigned short* Abf = (unsigned short*)ws;                                 // 16 MB
    unsigned short* Bbf = (unsigned short*)(ws + (size_t)B_ROWS * KP * 2);     // 2 MB
    float* xn = (float*)(ws + (size_t)(B_ROWS + C_ROWS) * KP * 2);             // 64 KB
    float* pn = (float*)((char*)xn + (size_t)B_ROWS * 4);                      // 8 KB
    (void)in_sizes; (void)n_in; (void)out_size; (void)ws_size;

    prep_kernel<<<B_ROWS + C_ROWS, 256, 0, stream>>>(x, pts, Abf, Bbf, xn, pn);

    dim3 grid(B_ROWS / BM, C_ROWS / BN);
    gemm_kernel<<<grid, 256, 0, stream>>>(Abf, Bbf, xn, pn, out);
}

// Round 5
// 196.132 us; speedup vs baseline: 1.4130x; 1.0296x over previous
//
#include <hip/hip_runtime.h>
#include <hip/hip_bf16.h>
#include <stdint.h>

#define B_ROWS 16384   // batch rows (M)
#define C_ROWS 2048    // class rows (N)
#define D_FULL 512     // input feature dim
#define KP     512     // padded K (511 real + 1 zero col)

#define BM 128
#define BN 128
#define BK 64          // 8 K-iters, 1 barrier each (double-buffered)

typedef __attribute__((ext_vector_type(8))) short bf16x8;
typedef __attribute__((ext_vector_type(4))) float f32x4;

typedef __attribute__((address_space(1))) void glb_void;
typedef __attribute__((address_space(3))) void lds_void;

// async global->LDS, 16B per lane; LDS dest = wave-uniform base + lane*16
__device__ __forceinline__ void gld16(const void* g, void* l) {
    __builtin_amdgcn_global_load_lds((glb_void*)(uintptr_t)g,
                                     (lds_void*)(uintptr_t)l, 16, 0, 0);
}

// ---------------------------------------------------------------------------
// Prep: per row, cast cols [1..511] -> bf16 (padded to 512 with trailing 0),
// and compute norm = sqrt(1 + sum(rest^2)) in fp32.
// ---------------------------------------------------------------------------
__global__ __launch_bounds__(256) void prep_kernel(
    const float* __restrict__ x, const float* __restrict__ pts,
    unsigned short* __restrict__ Abf, unsigned short* __restrict__ Bbf,
    float* __restrict__ xn, float* __restrict__ pn)
{
    int row = blockIdx.x;
    const float* src;
    unsigned short* dst;
    float* nrm;
    if (row < B_ROWS) {
        src = x + (size_t)row * D_FULL;
        dst = Abf + (size_t)row * KP;
        nrm = xn + row;
    } else {
        int r = row - B_ROWS;
        src = pts + (size_t)r * D_FULL;
        dst = Bbf + (size_t)r * KP;
        nrm = pn + r;
    }
    int t = threadIdx.x;
    float v0 = src[2 * t + 1];
    float v1 = (t < 255) ? src[2 * t + 2] : 0.0f;    // k==511 -> pad 0
    __hip_bfloat16 b0 = __float2bfloat16(v0);
    __hip_bfloat16 b1 = __float2bfloat16(v1);
    union { unsigned short u[2]; unsigned int w; } pack;
    pack.u[0] = *(unsigned short*)&b0;
    pack.u[1] = *(unsigned short*)&b1;
    *(unsigned int*)&dst[2 * t] = pack.w;
    float ss = v0 * v0 + v1 * v1;
    #pragma unroll
    for (int off = 32; off > 0; off >>= 1) ss += __shfl_down(ss, off);
    __shared__ float red[4];
    if ((t & 63) == 0) red[t >> 6] = ss;
    __syncthreads();
    if (t == 0) nrm[0] = sqrtf(1.0f + red[0] + red[1] + red[2] + red[3]);
}

// ---------------------------------------------------------------------------
// GEMM: C[m][n] = sum_k A[m][k]*B[n][k], both K-major. 128x128 tile, 4 waves
// 2x2, wave 64x64 via 4x4 of 16x16x32 bf16.
// DOUBLE-BUFFERED LDS at BK=64 (64 KB), ONE barrier per iter:
//   barrier; stage(k+1 -> buf^1) async; ds_read+MFMA on buf
// so the implicit vmcnt(0) drain at each barrier waits on loads issued a full
// compute phase (~700 cyc, 32 MFMA) earlier -> drain ~free.
// Round-2's VERIFIED swizzle (row stride 128B = 32 banks): 16B-chunk position
// p of row r holds global chunk p ^ (r&7); fragment reads are 2-way (free).
// Epilogue: out = -arccosh(max(x0[m]*p0[n] - acc, 1+eps))
// ---------------------------------------------------------------------------
__global__ __launch_bounds__(256, 2) void gemm_kernel(
    const unsigned short* __restrict__ A,   // [B_ROWS][KP] bf16
    const unsigned short* __restrict__ Bm,  // [C_ROWS][KP] bf16
    const float* __restrict__ xn, const float* __restrict__ pn,
    float* __restrict__ out)
{
    __shared__ unsigned short As[2][BM * BK];   // 2 x 16 KB
    __shared__ unsigned short Bs[2][BN * BK];   // 2 x 16 KB

    const int tid  = threadIdx.x;
    const int wave = tid >> 6;
    const int lane = tid & 63;
    const int wm   = wave >> 1;        // 0..1
    const int wn   = wave & 1;         // 0..1
    const int lrow = lane & 15;
    const int quad = lane >> 4;        // 0..3

    const int bm0 = blockIdx.x * BM;
    const int bn0 = blockIdx.y * BN;

    // staging (round-2 verified): wave covers 32 rows/tile in 4 issues of 8
    // rows; lane's LDS chunk pos = lane&7, row-within-8 = lane>>3; global
    // source chunk = (lane&7) ^ (row&7). (+8i preserves row&7.)
    const int srow = wave * 32 + (lane >> 3);
    const int scol = (((lane & 7) ^ ((lane >> 3) & 7)) << 3);

    const unsigned short* gA = A  + (size_t)(bm0 + srow) * KP + scol;
    const unsigned short* gB = Bm + (size_t)(bn0 + srow) * KP + scol;

    f32x4 acc[4][4] = {};

    // prologue: stage k-block 0 into buf 0
    #pragma unroll
    for (int i = 0; i < 4; ++i) {
        gld16(gA + (size_t)(i * 8) * KP, &As[0][(wave * 32 + i * 8) * BK]);
        gld16(gB + (size_t)(i * 8) * KP, &Bs[0][(wave * 32 + i * 8) * BK]);
    }

    #pragma unroll 2
    for (int it = 0; it < KP / BK; ++it) {
        const int buf = it & 1;
        __syncthreads();   // drains buf's staging (issued a full compute phase ago)
        if (it + 1 < KP / BK) {
            const int k1 = (it + 1) * BK;
            #pragma unroll
            for (int i = 0; i < 4; ++i) {
                gld16(gA + (size_t)(i * 8) * KP + k1, &As[buf ^ 1][(wave * 32 + i * 8) * BK]);
                gld16(gB + (size_t)(i * 8) * KP + k1, &Bs[buf ^ 1][(wave * 32 + i * 8) * BK]);
            }
        }
        #pragma unroll
        for (int kk = 0; kk < BK; kk += 32) {
            const int ch0 = kk >> 3;             // chunk base: 0 or 4
            bf16x8 af[4], bfr[4];
            #pragma unroll
            for (int mi = 0; mi < 4; ++mi) {
                int r = wm * 64 + mi * 16 + lrow;
                af[mi] = *(const bf16x8*)&As[buf][r * BK + (((ch0 + quad) ^ (lrow & 7)) << 3)];
            }
            #pragma unroll
            for (int ni = 0; ni < 4; ++ni) {
                int r = wn * 64 + ni * 16 + lrow;
                bfr[ni] = *(const bf16x8*)&Bs[buf][r * BK + (((ch0 + quad) ^ (lrow & 7)) << 3)];
            }
            #pragma unroll
            for (int mi = 0; mi < 4; ++mi)
                #pragma unroll
                for (int ni = 0; ni < 4; ++ni)
                    acc[mi][ni] = __builtin_amdgcn_mfma_f32_16x16x32_bf16(
                        af[mi], bfr[ni], acc[mi][ni], 0, 0, 0);
        }
    }

    // epilogue: C/D layout col = lane&15, row = quad*4 + reg
    float pv[4];
    #pragma unroll
    for (int ni = 0; ni < 4; ++ni)
        pv[ni] = pn[bn0 + wn * 64 + ni * 16 + lrow];

    #pragma unroll
    for (int mi = 0; mi < 4; ++mi) {
        #pragma unroll
        for (int r = 0; r < 4; ++r) {
            int row = bm0 + wm * 64 + mi * 16 + quad * 4 + r;
            float xv = xn[row];
            size_t base = (size_t)row * C_ROWS + bn0 + wn * 64 + lrow;
            #pragma unroll
            for (int ni = 0; ni < 4; ++ni) {
                float z = fmaf(xv, pv[ni], -acc[mi][ni][r]);
                z = fmaxf(z, 1.0f + 1e-7f);
                // arccosh(z) = log(z + sqrt(z^2-1)); z >= ~26 here, no cancellation
                out[base + ni * 16] = -__logf(z + __fsqrt_rn(z * z - 1.0f));
            }
        }
    }
}

extern "C" void kernel_launch(void* const* d_in, const int* in_sizes, int n_in,
                              void* d_out, int out_size, void* d_ws, size_t ws_size,
                              hipStream_t stream) {
    const float* x   = (const float*)d_in[0];
    const float* pts = (const float*)d_in[1];
    float* out = (float*)d_out;

    char* ws = (char*)d_ws;
    unsigned short* Abf = (unsigned short*)ws;                                 // 16 MB
    unsigned short* Bbf = (unsigned short*)(ws + (size_t)B_ROWS * KP * 2);     // 2 MB
    float* xn = (float*)(ws + (size_t)(B_ROWS + C_ROWS) * KP * 2);             // 64 KB
    float* pn = (float*)((char*)xn + (size_t)B_ROWS * 4);                      // 8 KB
    (void)in_sizes; (void)n_in; (void)out_size; (void)ws_size;

    prep_kernel<<<B_ROWS + C_ROWS, 256, 0, stream>>>(x, pts, Abf, Bbf, xn, pn);

    dim3 grid(B_ROWS / BM, C_ROWS / BN);
    gemm_kernel<<<grid, 256, 0, stream>>>(Abf, Bbf, xn, pn, out);
}